// Round 3
// baseline (301.990 us; speedup 1.0000x reference)
//
#include <hip/hip_runtime.h>
#include <hip/hip_bf16.h>

// Grouped GEMM: out[n,g,k] = sum_d x[n*8+g, d] * W[g, k, d]
// 256x256 tile, BK=64, 8 waves (2Mx4N), 4 phases/K-tile = (ks, row-half).
// Deep staged pipeline: A(t+1) loads issued P0, cvt+LDS-write P2-post;
// B(t+1) issued P1, written P3-post -> ~2.5-phase in-flight window so the
// implicit vmcnt waits are counted, not drains (T4). XOR-swizzled LDS (T2),
// setprio around MFMA (T5), group-per-XCD swizzle (T1), raw barriers.

namespace {

constexpr int NG   = 8;
constexpr int DIN  = 1024;
constexpr int DOUT = 1024;
constexpr int BM   = 256;
constexpr int BN   = 256;
constexpr int BK   = 64;
constexpr int NKT  = DIN / BK;            // 16
constexpr int ROWB = BK * 2;              // 128 B per LDS row
constexpr int LDS_TILE  = BM * ROWB;      // 32 KiB per tile buffer
constexpr int LDS_BYTES = 4 * LDS_TILE;   // 128 KiB: A0,A1,B0,B1

typedef __attribute__((ext_vector_type(8))) short bf16x8;
typedef __attribute__((ext_vector_type(4))) float f32x4;

__device__ __forceinline__ uint2 pack_bf16x4(f32x4 v) {
  union { __hip_bfloat162 h2[2]; uint2 u; } p;
  p.h2[0] = __float22bfloat162_rn(make_float2(v.x, v.y));
  p.h2[1] = __float22bfloat162_rn(make_float2(v.z, v.w));
  return p.u;
}

#define FENCE() asm volatile("" ::: "memory")
#define BAR()   do { FENCE(); __builtin_amdgcn_s_barrier(); FENCE(); } while (0)
#define LGKM0() asm volatile("s_waitcnt lgkmcnt(0)" ::: "memory")
#define MFMA_(a, b, c) __builtin_amdgcn_mfma_f32_16x16x32_bf16((a), (b), (c), 0, 0, 0)

// phase (KS, MH): ds_read 4 A-frags (rows MH*4..+4, k-sub KS) -> PRE ->
// barrier -> lgkm(0) -> sched fence -> setprio(1) -> 16 MFMA -> setprio(0)
// -> POST -> barrier
#define QPHASE(KS, MH, PRE, POST)                                              \
  do {                                                                         \
    const int cx_ = (KS) ? colx1 : colx0;                                      \
    bf16x8 af0 = *(const bf16x8*)(cA + aRow0 + ((MH)*4+0)*2048 + cx_);         \
    bf16x8 af1 = *(const bf16x8*)(cA + aRow0 + ((MH)*4+1)*2048 + cx_);         \
    bf16x8 af2 = *(const bf16x8*)(cA + aRow0 + ((MH)*4+2)*2048 + cx_);         \
    bf16x8 af3 = *(const bf16x8*)(cA + aRow0 + ((MH)*4+3)*2048 + cx_);         \
    PRE                                                                        \
    BAR();                                                                     \
    LGKM0();                                                                   \
    __builtin_amdgcn_sched_barrier(0);                                         \
    __builtin_amdgcn_s_setprio(1);                                             \
    _Pragma("unroll")                                                          \
    for (int n = 0; n < 4; ++n) {                                              \
      acc[(MH)*4+0][n] = MFMA_(af0, bfr[n], acc[(MH)*4+0][n]);                 \
      acc[(MH)*4+1][n] = MFMA_(af1, bfr[n], acc[(MH)*4+1][n]);                 \
      acc[(MH)*4+2][n] = MFMA_(af2, bfr[n], acc[(MH)*4+2][n]);                 \
      acc[(MH)*4+3][n] = MFMA_(af3, bfr[n], acc[(MH)*4+3][n]);                 \
    }                                                                          \
    __builtin_amdgcn_s_setprio(0);                                             \
    POST                                                                       \
    BAR();                                                                     \
  } while (0)

__global__ __launch_bounds__(512, 2)
void grouped_gemm_8p(const float* __restrict__ X,
                     const float* __restrict__ W,
                     float* __restrict__ O) {
  extern __shared__ char smem[];
  char* const smA = smem;                  // [2][256][64] bf16, swizzled
  char* const smB = smem + 2 * LDS_TILE;

  // ---- block mapping: group == XCD (1024 blocks, 128/XCD chunk), bijective
  const int bid = (int)blockIdx.x;
  const int swz = (bid & 7) * 128 + (bid >> 3);
  const int jt = swz & 3;                  // col tile  [0,4)  fastest: A reuse
  const int it = (swz >> 2) & 31;          // row tile  [0,32)
  const int g  = swz >> 7;                 // group     [0,8)  == XCD

  const int n0 = it * BM;
  const int c0 = jt * BN;

  const int tid  = (int)threadIdx.x;
  const int lane = tid & 63;
  const int wid  = tid >> 6;               // 8 waves: 2(M) x 4(N)
  const int wr   = wid >> 2;
  const int wc   = wid & 3;

  // staging map: 16 lanes x float4 = 64 cols; 32 rows/pass; 8 passes
  const int s_lane = tid & 15;
  const int s_row  = tid >> 4;

  const float* Ag = X + ((size_t)(n0 + s_row) * NG + g) * DIN + s_lane * 4;
  const float* Bg = W + (size_t)g * DOUT * DIN + (size_t)(c0 + s_row) * DIN
                      + s_lane * 4;
  constexpr size_t ASTR = (size_t)32 * NG * DIN;   // 32 tile-rows per pass
  constexpr size_t BSTR = (size_t)32 * DIN;

  // swizzled LDS write base (row&7 invariant across passes: 32 % 8 == 0)
  const int wb0 = s_row * ROWB + ((s_lane * 8) ^ ((s_row & 7) << 4));

  // fragment addressing (XOR involution matches the write side)
  const int fr = lane & 15;
  const int fq = lane >> 4;
  const int swzm  = (fr & 7) << 4;
  const int colx0 = (fq * 16) ^ swzm;          // ks=0
  const int colx1 = (64 + fq * 16) ^ swzm;     // ks=1
  const int aRow0 = (wr * 128 + fr) * ROWB;
  const int bRow0 = (wc * 64  + fr) * ROWB;

  f32x4 aS[8], bS[8];
  f32x4 acc[8][4];
#pragma unroll
  for (int m = 0; m < 8; ++m)
#pragma unroll
    for (int n = 0; n < 4; ++n) acc[m][n] = (f32x4){0.f, 0.f, 0.f, 0.f};

  // ---- prologue: stage tile 0 into buffer 0
#pragma unroll
  for (int p = 0; p < 8; ++p) {
    aS[p] = *(const f32x4*)(Ag + p * ASTR);
    bS[p] = *(const f32x4*)(Bg + p * BSTR);
  }
#pragma unroll
  for (int p = 0; p < 8; ++p) {
    *(uint2*)(smA + wb0 + p * 4096) = pack_bf16x4(aS[p]);
    *(uint2*)(smB + wb0 + p * 4096) = pack_bf16x4(bS[p]);
  }
  LGKM0();
  BAR();

#pragma unroll 2
  for (int t = 0; t < NKT; ++t) {
    char* const cA = smA + (t & 1) * LDS_TILE;
    char* const cB = smB + (t & 1) * LDS_TILE;
    char* const nA = smA + ((t & 1) ^ 1) * LDS_TILE;
    char* const nB = smB + ((t & 1) ^ 1) * LDS_TILE;
    const bool stage = (t + 1) < NKT;

    // B fragments, k-subtile 0 (16 VGPR; reloaded for ks=1 at P2)
    bf16x8 bfr[4];
#pragma unroll
    for (int n = 0; n < 4; ++n)
      bfr[n] = *(const bf16x8*)(cB + bRow0 + n * 2048 + colx0);

    // P0 (ks0, rows 0-3): issue A(t+1) loads -> in flight ~2.5 phases
    QPHASE(0, 0,
      { if (stage) {
          const float* An = Ag + (size_t)(t + 1) * BK;
          _Pragma("unroll")
          for (int p = 0; p < 8; ++p) aS[p] = *(const f32x4*)(An + p * ASTR);
        } },
      { });

    // P1 (ks0, rows 4-7): issue B(t+1) loads -> in flight ~2.5 phases
    QPHASE(0, 1,
      { if (stage) {
          const float* Bn = Bg + (size_t)(t + 1) * BK;
          _Pragma("unroll")
          for (int p = 0; p < 8; ++p) bS[p] = *(const f32x4*)(Bn + p * BSTR);
        } },
      { });

    // P2 (ks1, rows 0-3): reload B-frags ks1; post-MFMA cvt+write A(t+1)
    // (compiler waits vmcnt(8): B's loads stay in flight -> counted, no drain)
    QPHASE(1, 0,
      { _Pragma("unroll")
        for (int n = 0; n < 4; ++n)
          bfr[n] = *(const bf16x8*)(cB + bRow0 + n * 2048 + colx1);
      },
      { if (stage) {
          _Pragma("unroll")
          for (int p = 0; p < 8; ++p)
            *(uint2*)(nA + wb0 + p * 4096) = pack_bf16x4(aS[p]);
        } });

    // P3 (ks1, rows 4-7): post-MFMA cvt+write B(t+1); drain LDS, publish
    QPHASE(1, 1, { },
      { if (stage) {
          _Pragma("unroll")
          for (int p = 0; p < 8; ++p)
            *(uint2*)(nB + wb0 + p * 4096) = pack_bf16x4(bS[p]);
        }
        LGKM0(); });
  }

  // ---- epilogue: C/D layout col = lane&15, row = (lane>>4)*4 + reg (m89)
#pragma unroll
  for (int m = 0; m < 8; ++m) {
#pragma unroll
    for (int r = 0; r < 4; ++r) {
      const int row = wr * 128 + m * 16 + fq * 4 + r;
      float* orow = O + ((size_t)(n0 + row) * NG + g) * DOUT + c0 + wc * 64;
#pragma unroll
      for (int n = 0; n < 4; ++n) {
        orow[n * 16 + fr] = acc[m][n][r];
      }
    }
  }
}

} // namespace

extern "C" void kernel_launch(void* const* d_in, const int* in_sizes, int n_in,
                              void* d_out, int out_size, void* d_ws, size_t ws_size,
                              hipStream_t stream) {
  (void)n_in; (void)d_ws; (void)ws_size; (void)out_size;
  const float* X = (const float*)d_in[0];
  const float* W = (const float*)d_in[1];
  float* O = (float*)d_out;

  const int tokens_total = in_sizes[0] / DIN;            // 65536
  const int ntok_per_g   = tokens_total / NG;            // 8192
  const int grid = NG * (ntok_per_g / BM) * (DOUT / BN); // 1024

  (void)hipFuncSetAttribute((const void*)grouped_gemm_8p,
                            hipFuncAttributeMaxDynamicSharedMemorySize,
                            LDS_BYTES);

  grouped_gemm_8p<<<dim3(grid), dim3(512), LDS_BYTES, stream>>>(X, W, O);
}

// Round 4
// 239.074 us; speedup vs baseline: 1.2632x; 1.2632x over previous
//
#include <hip/hip_runtime.h>
#include <hip/hip_bf16.h>

// Grouped GEMM: out[n,g,k] = sum_d x[n*8+g, d] * W[g, k, d]
// Two kernels:
//  1) cvt_w: W f32 -> bf16 into d_ws, tiled [g][jt][kt] in swizzled LDS-image
//     byte order (so global_load_lds with a LINEAR dest reproduces the
//     swizzled LDS tile -- rule #21 both-sides form).
//  2) gemm: 256x256 tile, BK=64, 8 waves, 4 phases/K-tile. B staged via
//     global_load_lds (0 regs); A reg-staged fp32->bf16 (cvt fused).
//     Counted vmcnt only (drain at tile boundary). T1/T2/T5 as before.

namespace {

constexpr int NG   = 8;
constexpr int DIN  = 1024;
constexpr int DOUT = 1024;
constexpr int BM   = 256;
constexpr int BN   = 256;
constexpr int BK   = 64;
constexpr int NKT  = DIN / BK;            // 16
constexpr int ROWB = BK * 2;              // 128 B per LDS row
constexpr int LDS_TILE  = BM * ROWB;      // 32 KiB per tile buffer
constexpr int LDS_BYTES = 4 * LDS_TILE;   // 128 KiB: A0,A1,B0,B1
constexpr int JTN  = DOUT / BN;           // 4 col panels
constexpr size_t WSB_BYTES = (size_t)NG * JTN * NKT * LDS_TILE;  // 16.78 MB

typedef __attribute__((ext_vector_type(8))) short bf16x8;
typedef __attribute__((ext_vector_type(4))) float f32x4;

__device__ __forceinline__ uint2 pack_bf16x4(f32x4 v) {
  union { __hip_bfloat162 h2[2]; uint2 u; } p;
  p.h2[0] = __float22bfloat162_rn(make_float2(v.x, v.y));
  p.h2[1] = __float22bfloat162_rn(make_float2(v.z, v.w));
  return p.u;
}

__device__ __forceinline__ void glds16(const void* g, void* l) {
  __builtin_amdgcn_global_load_lds(
      (const __attribute__((address_space(1))) unsigned int*)g,
      (__attribute__((address_space(3))) unsigned int*)l, 16, 0, 0);
}

#define FENCE() asm volatile("" ::: "memory")
#define BAR()   do { FENCE(); __builtin_amdgcn_s_barrier(); FENCE(); } while (0)
#define LGKM0() asm volatile("s_waitcnt lgkmcnt(0)" ::: "memory")
#define VM0()   asm volatile("s_waitcnt vmcnt(0)" ::: "memory")
#define MFMA_(a, b, c) __builtin_amdgcn_mfma_f32_16x16x32_bf16((a), (b), (c), 0, 0, 0)

// ---------------- kernel 1: W f32 -> bf16 swizzled-tile image in ws --------
__global__ __launch_bounds__(256)
void cvt_w_kernel(const float* __restrict__ W, char* __restrict__ wsB) {
  const int q    = (int)blockIdx.x * 256 + (int)threadIdx.x;  // u32 index
  const int tile = q >> 13;            // [g*4+jt]*16+kt
  const int q13  = q & 8191;
  const int r    = q13 >> 5;           // LDS row 0..255
  const int cp   = q13 & 31;           // col-pair 0..31 (cols 2cp, 2cp+1)
  const int g    = tile >> 6;
  const int jt   = (tile >> 4) & 3;
  const int kt   = tile & 15;

  const float2 s = *(const float2*)(
      W + ((size_t)(g * DOUT + jt * 256 + r)) * DIN + kt * 64 + 2 * cp);
  union { __hip_bfloat162 h; unsigned u; } pk;
  pk.h = __float22bfloat162_rn(make_float2(s.x, s.y));

  const int swz = (r & 7) << 4;
  const int dstByte = r * 128 + (((cp >> 2) * 16) ^ swz) + (cp & 3) * 4;
  *(unsigned*)(wsB + (size_t)tile * LDS_TILE + dstByte) = pk.u;
}

// ---------------- kernel 2: grouped GEMM ----------------------------------
// phase (KS, MH): ds_read 4 A-frags -> PRE -> barrier -> lgkm(0) -> fence ->
// setprio(1) -> 16 MFMA -> setprio(0) -> POST -> barrier
#define QPHASE(KS, MH, PRE, POST)                                              \
  do {                                                                         \
    const int cx_ = (KS) ? colx1 : colx0;                                      \
    bf16x8 af0 = *(const bf16x8*)(cA + aRow0 + ((MH)*4+0)*2048 + cx_);         \
    bf16x8 af1 = *(const bf16x8*)(cA + aRow0 + ((MH)*4+1)*2048 + cx_);         \
    bf16x8 af2 = *(const bf16x8*)(cA + aRow0 + ((MH)*4+2)*2048 + cx_);         \
    bf16x8 af3 = *(const bf16x8*)(cA + aRow0 + ((MH)*4+3)*2048 + cx_);         \
    PRE                                                                        \
    BAR();                                                                     \
    LGKM0();                                                                   \
    __builtin_amdgcn_sched_barrier(0);                                         \
    __builtin_amdgcn_s_setprio(1);                                             \
    _Pragma("unroll")                                                          \
    for (int n = 0; n < 4; ++n) {                                              \
      acc[(MH)*4+0][n] = MFMA_(af0, bfr[n], acc[(MH)*4+0][n]);                 \
      acc[(MH)*4+1][n] = MFMA_(af1, bfr[n], acc[(MH)*4+1][n]);                 \
      acc[(MH)*4+2][n] = MFMA_(af2, bfr[n], acc[(MH)*4+2][n]);                 \
      acc[(MH)*4+3][n] = MFMA_(af3, bfr[n], acc[(MH)*4+3][n]);                 \
    }                                                                          \
    __builtin_amdgcn_s_setprio(0);                                             \
    POST                                                                       \
    BAR();                                                                     \
  } while (0)

template <bool WSB>
__global__ __launch_bounds__(512, 2)
void grouped_gemm_8p(const float* __restrict__ X,
                     const float* __restrict__ W,
                     const char* __restrict__ wsB,
                     float* __restrict__ O) {
  extern __shared__ char smem[];
  char* const smA = smem;                  // [2][256][64] bf16, swizzled
  char* const smB = smem + 2 * LDS_TILE;

  // ---- block mapping: group == XCD (1024 blocks, 128/XCD chunk), bijective
  const int bid = (int)blockIdx.x;
  const int swz = (bid & 7) * 128 + (bid >> 3);
  const int jt = swz & 3;                  // col panel [0,4)  fastest: A reuse
  const int it = (swz >> 2) & 31;          // row tile  [0,32)
  const int g  = swz >> 7;                 // group     [0,8)  == XCD

  const int n0 = it * BM;
  const int c0 = jt * BN;

  const int tid  = (int)threadIdx.x;
  const int lane = tid & 63;
  const int wid  = tid >> 6;               // 8 waves: 2(M) x 4(N)
  const int wr   = wid >> 2;
  const int wc   = wid & 3;

  // staging map (A): 16 lanes x float4 = 64 cols; 32 rows/pass; 8 passes
  const int s_lane = tid & 15;
  const int s_row  = tid >> 4;

  const float* Ag = X + ((size_t)(n0 + s_row) * NG + g) * DIN + s_lane * 4;
  constexpr size_t ASTR = (size_t)32 * NG * DIN;   // 32 tile-rows per pass

  // fallback-path B staging base
  const float* Bg = W + (size_t)g * DOUT * DIN + (size_t)(c0 + s_row) * DIN
                      + s_lane * 4;
  constexpr size_t BSTR = (size_t)32 * DIN;

  // ws-path B tile stream base + per-thread 16B slot
  const char* BgT = wsB + ((size_t)(g * JTN + jt) * NKT) * LDS_TILE;
  const int bOff = tid * 16;               // pass stride 8192 (512*16)

  // swizzled LDS write base for A (row&7 invariant: 32 % 8 == 0)
  const int wb0 = s_row * ROWB + ((s_lane * 8) ^ ((s_row & 7) << 4));

  // fragment addressing (XOR involution matches write/image side)
  const int fr = lane & 15;
  const int fq = lane >> 4;
  const int swzm  = (fr & 7) << 4;
  const int colx0 = (fq * 16) ^ swzm;          // ks=0
  const int colx1 = (64 + fq * 16) ^ swzm;     // ks=1
  const int aRow0 = (wr * 128 + fr) * ROWB;
  const int bRow0 = (wc * 64  + fr) * ROWB;

  f32x4 aS[8], bS[8];
  f32x4 acc[8][4];
#pragma unroll
  for (int m = 0; m < 8; ++m)
#pragma unroll
    for (int n = 0; n < 4; ++n) acc[m][n] = (f32x4){0.f, 0.f, 0.f, 0.f};

  // ---- prologue: stage tile 0 into buffer 0
  if (WSB) {
#pragma unroll
    for (int p = 0; p < 4; ++p)
      glds16(BgT + bOff + p * 8192, smB + bOff + p * 8192);
  } else {
#pragma unroll
    for (int p = 0; p < 8; ++p) bS[p] = *(const f32x4*)(Bg + p * BSTR);
  }
#pragma unroll
  for (int p = 0; p < 8; ++p) aS[p] = *(const f32x4*)(Ag + p * ASTR);
#pragma unroll
  for (int p = 0; p < 8; ++p)
    *(uint2*)(smA + wb0 + p * 4096) = pack_bf16x4(aS[p]);
  if (!WSB) {
#pragma unroll
    for (int p = 0; p < 8; ++p)
      *(uint2*)(smB + wb0 + p * 4096) = pack_bf16x4(bS[p]);
  }
  VM0();     // B DMA (ws path) complete
  LGKM0();
  BAR();

#pragma unroll 2
  for (int t = 0; t < NKT; ++t) {
    char* const cA = smA + (t & 1) * LDS_TILE;
    char* const cB = smB + (t & 1) * LDS_TILE;
    char* const nA = smA + ((t & 1) ^ 1) * LDS_TILE;
    char* const nB = smB + ((t & 1) ^ 1) * LDS_TILE;
    const bool stage = (t + 1) < NKT;

    // B fragments, k-subtile 0 (16 VGPR; reloaded for ks=1 at P2)
    bf16x8 bfr[4];
#pragma unroll
    for (int n = 0; n < 4; ++n)
      bfr[n] = *(const bf16x8*)(cB + bRow0 + n * 2048 + colx0);

    // P0 (ks0, rows 0-3): issue A(t+1) reg-loads + B(t+1) LDS-DMA (ws path)
    QPHASE(0, 0,
      { if (stage) {
          const float* An = Ag + (size_t)(t + 1) * BK;
          _Pragma("unroll")
          for (int p = 0; p < 8; ++p) aS[p] = *(const f32x4*)(An + p * ASTR);
          if (WSB) {
            const char* Bn = BgT + (size_t)(t + 1) * LDS_TILE;
            _Pragma("unroll")
            for (int p = 0; p < 4; ++p)
              glds16(Bn + bOff + p * 8192, nB + bOff + p * 8192);
          }
        } },
      { });

    // P1 (ks0, rows 4-7): fallback path issues B(t+1) reg-loads
    QPHASE(0, 1,
      { if (!WSB && stage) {
          const float* Bn = Bg + (size_t)(t + 1) * BK;
          _Pragma("unroll")
          for (int p = 0; p < 8; ++p) bS[p] = *(const f32x4*)(Bn + p * BSTR);
        } },
      { });

    // P2 (ks1, rows 0-3): reload B-frags ks1; post-MFMA cvt+write A(t+1)
    // (A's vmcnt wait is counted -- B DMA stays outstanding)
    QPHASE(1, 0,
      { _Pragma("unroll")
        for (int n = 0; n < 4; ++n)
          bfr[n] = *(const bf16x8*)(cB + bRow0 + n * 2048 + colx1);
      },
      { if (stage) {
          _Pragma("unroll")
          for (int p = 0; p < 8; ++p)
            *(uint2*)(nA + wb0 + p * 4096) = pack_bf16x4(aS[p]);
        } });

    // P3 (ks1, rows 4-7): fallback cvt+write B(t+1); drain LDS writes and
    // (ws path) the B DMA, then publish via the closing barrier
    QPHASE(1, 1, { },
      { if (!WSB && stage) {
          _Pragma("unroll")
          for (int p = 0; p < 8; ++p)
            *(uint2*)(nB + wb0 + p * 4096) = pack_bf16x4(bS[p]);
        }
        LGKM0();
        if (WSB && stage) { VM0(); } });
  }

  // ---- epilogue: C/D layout col = lane&15, row = (lane>>4)*4 + reg (m89)
#pragma unroll
  for (int m = 0; m < 8; ++m) {
#pragma unroll
    for (int r = 0; r < 4; ++r) {
      const int row = wr * 128 + m * 16 + fq * 4 + r;
      float* orow = O + ((size_t)(n0 + row) * NG + g) * DOUT + c0 + wc * 64;
#pragma unroll
      for (int n = 0; n < 4; ++n) {
        orow[n * 16 + fr] = acc[m][n][r];
      }
    }
  }
}

} // namespace

extern "C" void kernel_launch(void* const* d_in, const int* in_sizes, int n_in,
                              void* d_out, int out_size, void* d_ws, size_t ws_size,
                              hipStream_t stream) {
  (void)n_in; (void)out_size;
  const float* X = (const float*)d_in[0];
  const float* W = (const float*)d_in[1];
  float* O = (float*)d_out;

  const int tokens_total = in_sizes[0] / DIN;            // 65536
  const int ntok_per_g   = tokens_total / NG;            // 8192
  const int grid = NG * (ntok_per_g / BM) * (DOUT / BN); // 1024

  if (ws_size >= WSB_BYTES) {
    const int cvt_grid = (int)(WSB_BYTES / 4 / 256);     // 16384
    cvt_w_kernel<<<dim3(cvt_grid), dim3(256), 0, stream>>>(W, (char*)d_ws);
    (void)hipFuncSetAttribute((const void*)grouped_gemm_8p<true>,
                              hipFuncAttributeMaxDynamicSharedMemorySize,
                              LDS_BYTES);
    grouped_gemm_8p<true><<<dim3(grid), dim3(512), LDS_BYTES, stream>>>(
        X, W, (const char*)d_ws, O);
  } else {
    (void)hipFuncSetAttribute((const void*)grouped_gemm_8p<false>,
                              hipFuncAttributeMaxDynamicSharedMemorySize,
                              LDS_BYTES);
    grouped_gemm_8p<false><<<dim3(grid), dim3(512), LDS_BYTES, stream>>>(
        X, W, nullptr, O);
  }
}